// Round 4
// baseline (512.533 us; speedup 1.0000x reference)
//
#include <hip/hip_runtime.h>

#define EMB 256
#define HD 32
#define SEQ 4096
#define NSPLIT 8      // key splits across blocks
#define KRANGE 512    // keys per block (shared by its 4 waves)
#define NT (KRANGE / 32)
#define NQROW 16384   // B*S
#define NBLK 1024u    // grid size; 4 blocks/CU x 256 CU = exactly resident

typedef _Float16 half8 __attribute__((ext_vector_type(8)));
typedef _Float16 half4v __attribute__((ext_vector_type(4)));
typedef _Float16 half2v __attribute__((ext_vector_type(2)));
typedef float floatx4 __attribute__((ext_vector_type(4)));
typedef float floatx16 __attribute__((ext_vector_type(16)));
typedef unsigned uint2v __attribute__((ext_vector_type(2)));

#define L2E 1.44269504088896340736f
#define SCALING 0.17677669529663687f   // 32^-0.5, applied POST-softmax
#define DEFER_THR 8.0f                 // exp2-domain defer-max threshold: p <= 2^8

__device__ __forceinline__ half8 mk8(unsigned a, unsigned b, unsigned c, unsigned d) {
  union { unsigned u[4]; half8 h; } z;
  z.u[0] = a; z.u[1] = b; z.u[2] = c; z.u[3] = d;
  return z.h;
}

// permlane32_swap semantics: a' = {a.lo, b.lo}, b' = {a.hi, b.hi}
__device__ __forceinline__ void plswap(unsigned& a, unsigned& b) {
#if __has_builtin(__builtin_amdgcn_permlane32_swap)
  uint2v r = __builtin_amdgcn_permlane32_swap(a, b, false, false);
  a = r[0]; b = r[1];
#else
  unsigned sa = (unsigned)__shfl_xor((int)a, 32);
  unsigned sb = (unsigned)__shfl_xor((int)b, 32);
  bool hi = (threadIdx.x & 32) != 0;
  unsigned na = hi ? sb : a;
  unsigned nb = hi ? b : sa;
  a = na; b = nb;
#endif
}

// sum of the two f16 halves of pk into acc (consistent with the f16 P fed to PV MFMA)
__device__ __forceinline__ float sum2(unsigned pk, float acc) {
  half2v a = __builtin_bit_cast(half2v, pk);
#if __has_builtin(__builtin_amdgcn_fdot2)
  half2v one; one[0] = (_Float16)1.f; one[1] = (_Float16)1.f;
  return __builtin_amdgcn_fdot2(a, one, acc, false);
#else
  return acc + (float)a[0] + (float)a[1];
#endif
}

// Hand-rolled grid barrier: sense-reversing, agent-scope acq/rel atomics.
// ACQ_REL arrival RMW chains all blocks' prior writes through `bar`; the last
// arriver's RELEASE store of gen publishes them; ACQUIRE spin-load invalidates
// stale L1/L2 in the waiter's CU/XCD. Spin has a fail-safe cap (~0.2 s): a
// residency surprise degrades to wrong-answer, never a hang.
__device__ __forceinline__ void gsync(unsigned* bar, unsigned* gen) {
  __syncthreads();   // emits s_waitcnt vmcnt(0): block's stores are in L2 before arrival
  if (threadIdx.x == 0) {
    unsigned g = __hip_atomic_load(gen, __ATOMIC_RELAXED, __HIP_MEMORY_SCOPE_AGENT);
    unsigned old = __hip_atomic_fetch_add(bar, 1u, __ATOMIC_ACQ_REL, __HIP_MEMORY_SCOPE_AGENT);
    if (old == NBLK - 1u) {
      __hip_atomic_store(bar, 0u, __ATOMIC_RELAXED, __HIP_MEMORY_SCOPE_AGENT);
      __hip_atomic_store(gen, g + 1u, __ATOMIC_RELEASE, __HIP_MEMORY_SCOPE_AGENT);
    } else {
      int guard = 0;
      while (__hip_atomic_load(gen, __ATOMIC_ACQUIRE, __HIP_MEMORY_SCOPE_AGENT) == g) {
        __builtin_amdgcn_s_sleep(8);
        if (++guard > (1 << 20)) break;
      }
    }
  }
  __syncthreads();
}

// ============================================================================
// Single mega-kernel, REGULAR launch: prep -> gsync -> qkv -> gsync -> attn
// -> gsync -> combine. 1024 blocks x 256 thr, 0 LDS, launch_bounds(256,4)
// => 4 blocks/CU, all 1024 co-resident.
// ============================================================================
__global__ __launch_bounds__(256, 4) void mega_kernel(const float* __restrict__ x,
                                                      const float* __restrict__ Wq,
                                                      const float* __restrict__ Wk,
                                                      const float* __restrict__ Wv,
                                                      _Float16* __restrict__ wsw,
                                                      _Float16* __restrict__ qw,
                                                      _Float16* __restrict__ kw,
                                                      _Float16* __restrict__ vt2,
                                                      _Float16* __restrict__ Op,
                                                      float* __restrict__ Mp,
                                                      float* __restrict__ Lp,
                                                      unsigned* __restrict__ barrier_ws,
                                                      float* __restrict__ out) {
  const int tid = threadIdx.x;
  const int bid = blockIdx.x;
  const int gid = bid * 256 + tid;
  unsigned* bar = barrier_ws;
  unsigned* gen = barrier_ws + 16;   // separate cache lines

  // ---------- Phase A: swizzle W into MFMA B-frag order (f16), Wq pre-scaled by L2E ----------
  if (gid < 24576) {
    int j    = gid & 7;
    int lane = (gid >> 3) & 63;
    int kc   = (gid >> 9) & 7;
    int half = (gid >> 12) & 1;
    int mat  = gid >> 13;
    const float* W = (mat == 0) ? Wq : ((mat == 1) ? Wk : Wv);
    int n = lane & 15, quad = lane >> 4;
    int e = kc * 32 + quad * 8 + j;
    int d = n + half * 16;
    float v = W[e * HD + d];
    if (mat == 0) v *= L2E;                   // exp2-domain scores for free
    wsw[gid] = (_Float16)v;
  }

  gsync(bar, gen);

  // ---------- Phase B: QKV projection. Task = (rowgroup16, matrix); 3072 of 4096 waves ----------
  {
    int wid = gid >> 6;
    if (wid < 3072) {
      int mat = wid >> 10;          // 0..2
      int rowbase = (wid & 1023) * 16;
      int lane = tid & 63;
      int n = lane & 15, quad = lane >> 4;

      floatx4 c0 = {0,0,0,0}, c1 = {0,0,0,0};
#pragma unroll
      for (int kc = 0; kc < 8; ++kc) {
        const float* xp = x + (size_t)(rowbase + n) * EMB + kc * 32 + quad * 8;
        float4 xa = *(const float4*)(xp);
        float4 xb = *(const float4*)(xp + 4);
        half8 a;
        a[0] = (_Float16)xa.x; a[1] = (_Float16)xa.y; a[2] = (_Float16)xa.z; a[3] = (_Float16)xa.w;
        a[4] = (_Float16)xb.x; a[5] = (_Float16)xb.y; a[6] = (_Float16)xb.z; a[7] = (_Float16)xb.w;
        half8 b0 = *(const half8*)(wsw + (((mat * 2 + 0) * 8 + kc) << 9) + (lane << 3));
        half8 b1 = *(const half8*)(wsw + (((mat * 2 + 1) * 8 + kc) << 9) + (lane << 3));
        c0 = __builtin_amdgcn_mfma_f32_16x16x32_f16(a, b0, c0, 0, 0, 0);
        c1 = __builtin_amdgcn_mfma_f32_16x16x32_f16(a, b1, c1, 0, 0, 0);
      }

      if (mat == 2) {
        int b = rowbase >> 12;
        int s0 = rowbase & (SEQ - 1);
        _Float16* vb = vt2 + (size_t)b * SEQ * HD;
#pragma unroll
        for (int r = 0; r < 4; ++r) {
          int s = s0 + quad * 4 + r;
          int blk = (s >> 3) << 8, sl = s & 7;   // key-block base (8 keys x 32 d), slot
          vb[blk + n * 8 + sl]        = (_Float16)c0[r];
          vb[blk + (n + 16) * 8 + sl] = (_Float16)c1[r];
        }
      } else {
        _Float16* dst = (mat == 0) ? qw : kw;
#pragma unroll
        for (int r = 0; r < 4; ++r) {
          int row = rowbase + quad * 4 + r;
          dst[row * HD + n]      = (_Float16)c0[r];
          dst[row * HD + n + 16] = (_Float16)c1[r];
        }
      }
    }
  }

  gsync(bar, gen);

  // ---------- Phase C: flash attention, 32x32x16 MFMA, O^T orientation ----------
  {
    const int w = tid >> 6, lane = tid & 63;
    const int n2 = lane & 31, h = lane >> 5;
    const int qb = bid & 127;
    const int sp = bid >> 7;
    const int b = qb >> 5;
    const int qrow0 = qb * 128 + w * 32;
    const int key0 = sp * KRANGE;

    const _Float16* kb = kw  + (size_t)(b * SEQ + key0) * HD;
    const _Float16* vb = vt2 + (size_t)b * SEQ * HD + (size_t)key0 * HD;

    // Q^T B-frags (pre-scaled by L2E): B[k=d][n=qrow=n2]
    half8 qf0 = *(const half8*)(qw + (qrow0 + n2) * HD + h * 8);
    half8 qf1 = *(const half8*)(qw + (qrow0 + n2) * HD + 16 + h * 8);

    floatx16 o;
#pragma unroll
    for (int r = 0; r < 16; ++r) o[r] = 0.f;
    const floatx16 zero16 = o;
    float m = -__builtin_huge_valf();      // deferred reference max (exp2 domain)
    float mtrue = -__builtin_huge_valf();  // true running max (for epilogue rescale)
    float l = 0.f;

    // prefetch tile 0. V^T A-frag: A[m=d=n2][k=key=8h+j]
    half8 ka0 = *(const half8*)(kb + (size_t)n2 * HD + h * 8);
    half8 ka1 = *(const half8*)(kb + (size_t)n2 * HD + 16 + h * 8);
    half8 va0 = *(const half8*)(vb + h * 256 + n2 * 8);
    half8 va1 = *(const half8*)(vb + 512 + h * 256 + n2 * 8);

#pragma unroll 4
    for (int kt = 0; kt < NT; ++kt) {
      int nxt = (kt + 1) & (NT - 1);
      const _Float16* kn = kb + (size_t)(nxt * 32 + n2) * HD;
      const _Float16* vn = vb + nxt * 1024;
      half8 nka0 = *(const half8*)(kn + h * 8);
      half8 nka1 = *(const half8*)(kn + 16 + h * 8);
      half8 nva0 = *(const half8*)(vn + h * 256 + n2 * 8);
      half8 nva1 = *(const half8*)(vn + 512 + h * 256 + n2 * 8);

      // S^T tile [32 keys x 32 qrows]
      floatx16 s = __builtin_amdgcn_mfma_f32_32x32x16_f16(ka0, qf0, zero16, 0, 0, 0);
      s = __builtin_amdgcn_mfma_f32_32x32x16_f16(ka1, qf1, s, 0, 0, 0);

      floatx4 s0 = {s[0], s[1], s[2], s[3]};
      floatx4 s1 = {s[4], s[5], s[6], s[7]};
      floatx4 s2 = {s[8], s[9], s[10], s[11]};
      floatx4 s3 = {s[12], s[13], s[14], s[15]};
      floatx4 t01 = __builtin_elementwise_max(s0, s1);
      floatx4 t23 = __builtin_elementwise_max(s2, s3);
      floatx4 t4  = __builtin_elementwise_max(t01, t23);
      float mm = fmaxf(fmaxf(t4[0], t4[1]), fmaxf(t4[2], t4[3]));
      mm = fmaxf(mm, __shfl_xor(mm, 32));
      mtrue = fmaxf(mtrue, mm);

      // defer-max: only rescale when some row's max grew past THR (wave-uniform branch)
      if (__any(mm > m + DEFER_THR)) {
        float mnew = fmaxf(m, mm);
        float alpha = __builtin_amdgcn_exp2f(m - mnew);
        m = mnew;
#pragma unroll
        for (int r = 0; r < 16; ++r) o[r] *= alpha;
        l *= alpha;
      }

      // p = exp2(s - m) <= 2^THR, pack consecutive-key pairs
      unsigned pk[8];
#pragma unroll
      for (int g = 0; g < 8; ++g) {
        float p0 = __builtin_amdgcn_exp2f(s[2 * g] - m);
        float p1 = __builtin_amdgcn_exp2f(s[2 * g + 1] - m);
        pk[g] = __builtin_bit_cast(unsigned, __builtin_amdgcn_cvt_pkrtz(p0, p1));
      }

      // l partial: own 16 keys via f16 dot2 (partner merged once after the loop)
      float lA = sum2(pk[3], sum2(pk[2], sum2(pk[1], sum2(pk[0], 0.f))));
      float lB = sum2(pk[7], sum2(pk[6], sum2(pk[5], sum2(pk[4], 0.f))));
      l += lA + lB;

      // P^T B-frags via permlane32_swap
      unsigned b00 = pk[0], b02 = pk[2]; plswap(b00, b02);
      unsigned b01 = pk[1], b03 = pk[3]; plswap(b01, b03);
      unsigned b10 = pk[4], b12 = pk[6]; plswap(b10, b12);
      unsigned b11 = pk[5], b13 = pk[7]; plswap(b11, b13);

      // O^T += V^T · P^T  (two key halves)
      o = __builtin_amdgcn_mfma_f32_32x32x16_f16(va0, mk8(b00, b01, b02, b03), o, 0, 0, 0);
      o = __builtin_amdgcn_mfma_f32_32x32x16_f16(va1, mk8(b10, b11, b12, b13), o, 0, 0, 0);

      ka0 = nka0; ka1 = nka1; va0 = nva0; va1 = nva1;
    }

    // epilogue: rescale to the true max so f16 Op cannot overflow (p_eff <= 1)
    float scale = __builtin_amdgcn_exp2f(m - mtrue);
    l *= scale;
    l = l + __shfl_xor(l, 32);

    size_t obase = ((size_t)(sp * NQROW + qrow0) + n2) * 32;
#pragma unroll
    for (int bb = 0; bb < 4; ++bb) {
      half4v pv;
      pv[0] = (_Float16)(o[4 * bb + 0] * scale);
      pv[1] = (_Float16)(o[4 * bb + 1] * scale);
      pv[2] = (_Float16)(o[4 * bb + 2] * scale);
      pv[3] = (_Float16)(o[4 * bb + 3] * scale);
      *(half4v*)&Op[obase + 8 * bb + 4 * h] = pv;
    }
    if (h == 0) {
      int mi = sp * NQROW + qrow0 + n2;
      Mp[mi] = mtrue;
      Lp[mi] = l;
    }
  }

  gsync(bar, gen);

  // ---------- Phase D: merge the 8 key-splits, normalize, scale ----------
  if (gid < 131072) {
    int dc = gid & 7, qrow = gid >> 3;
    float mv[NSPLIT];
    float ms = -__builtin_huge_valf();
#pragma unroll
    for (int sp = 0; sp < NSPLIT; ++sp) {
      mv[sp] = Mp[sp * NQROW + qrow];
      ms = fmaxf(ms, mv[sp]);
    }
    float L = 0.f;
    floatx4 O = {0.f, 0.f, 0.f, 0.f};
#pragma unroll
    for (int sp = 0; sp < NSPLIT; ++sp) {
      float ww = __builtin_amdgcn_exp2f(mv[sp] - ms);
      L += ww * Lp[sp * NQROW + qrow];
      half4v ov = *(const half4v*)&Op[((size_t)(sp * NQROW + qrow)) * 32 + dc * 4];
#pragma unroll
      for (int r = 0; r < 4; ++r) O[r] += ww * (float)ov[r];
    }
    float inv = SCALING / L;
    floatx4 res = {O[0] * inv, O[1] * inv, O[2] * inv, O[3] * inv};
    *(floatx4*)&out[qrow * HD + dc * 4] = res;
  }
}

extern "C" void kernel_launch(void* const* d_in, const int* in_sizes, int n_in,
                              void* d_out, int out_size, void* d_ws, size_t ws_size,
                              hipStream_t stream) {
  const float* x  = (const float*)d_in[0];
  const float* Wq = (const float*)d_in[1];
  const float* Wk = (const float*)d_in[2];
  const float* Wv = (const float*)d_in[3];
  float* out = (float*)d_out;

  _Float16* wsw = (_Float16*)d_ws;          // 24576 f16
  _Float16* qw  = wsw + 24576;              // [16384][32]
  _Float16* kw  = qw + NQROW * HD;          // [16384][32]
  _Float16* vt2 = kw + NQROW * HD;          // [4][512][32][8] key-tiled V
  _Float16* Op  = vt2 + NQROW * HD;         // [8][16384][32] f16 (8 MB)
  float* Mp = (float*)(Op + (size_t)NSPLIT * NQROW * 32);  // [8][16384]
  float* Lp = Mp + NSPLIT * NQROW;                         // [8][16384]
  unsigned* barrier_ws = (unsigned*)(Lp + NSPLIT * NQROW); // 2 cells, separate lines

  // zero the barrier cells in-stream (graph-capturable; replay-safe vs re-poison)
  hipMemsetAsync(barrier_ws, 0, 128, stream);
  mega_kernel<<<NBLK, 256, 0, stream>>>(x, Wq, Wk, Wv, wsw, qw, kw, vt2,
                                        Op, Mp, Lp, barrier_ws, out);
}

// Round 5
// 142.357 us; speedup vs baseline: 3.6003x; 3.6003x over previous
//
#include <hip/hip_runtime.h>

#define EMB 256
#define HD 32
#define SEQ 4096
#define NSPLIT 8      // key splits across blocks
#define KRANGE 512    // keys per block (shared by its 4 waves)
#define NT (KRANGE / 32)
#define NQROW 16384   // B*S

typedef _Float16 half8 __attribute__((ext_vector_type(8)));
typedef _Float16 half4v __attribute__((ext_vector_type(4)));
typedef _Float16 half2v __attribute__((ext_vector_type(2)));
typedef float floatx4 __attribute__((ext_vector_type(4)));
typedef float floatx16 __attribute__((ext_vector_type(16)));
typedef unsigned uint2v __attribute__((ext_vector_type(2)));

#define L2E 1.44269504088896340736f
#define SCALING 0.17677669529663687f   // 32^-0.5, applied POST-softmax
#define DEFER_THR 8.0f                 // exp2-domain defer-max threshold: p <= 2^8

__device__ __forceinline__ half8 mk8(unsigned a, unsigned b, unsigned c, unsigned d) {
  union { unsigned u[4]; half8 h; } z;
  z.u[0] = a; z.u[1] = b; z.u[2] = c; z.u[3] = d;
  return z.h;
}

// permlane32_swap semantics: a' = {a.lo, b.lo}, b' = {a.hi, b.hi}
__device__ __forceinline__ void plswap(unsigned& a, unsigned& b) {
#if __has_builtin(__builtin_amdgcn_permlane32_swap)
  uint2v r = __builtin_amdgcn_permlane32_swap(a, b, false, false);
  a = r[0]; b = r[1];
#else
  unsigned sa = (unsigned)__shfl_xor((int)a, 32);
  unsigned sb = (unsigned)__shfl_xor((int)b, 32);
  bool hi = (threadIdx.x & 32) != 0;
  unsigned na = hi ? sb : a;
  unsigned nb = hi ? b : sa;
  a = na; b = nb;
#endif
}

// sum of the two f16 halves of pk into acc (consistent with the f16 P fed to PV MFMA)
__device__ __forceinline__ float sum2(unsigned pk, float acc) {
  half2v a = __builtin_bit_cast(half2v, pk);
#if __has_builtin(__builtin_amdgcn_fdot2)
  half2v one; one[0] = (_Float16)1.f; one[1] = (_Float16)1.f;
  return __builtin_amdgcn_fdot2(a, one, acc, false);
#else
  return acc + (float)a[0] + (float)a[1];
#endif
}

// ---------------- Kernel 1: fused W-swizzle (LDS) + QKV projection ----------------
// Each block swizzles all of W (96 KB fp32, L2-hot after block 0) into a 48 KB f16
// LDS image laid out in MFMA B-frag order, then runs the round-2 qkv body with
// ds_read_b128 fragment loads. Also zero-inits the split-K counters for attn.
__global__ __launch_bounds__(256) void qkv_kernel(const float* __restrict__ x,
                                                  const float* __restrict__ Wq,
                                                  const float* __restrict__ Wk,
                                                  const float* __restrict__ Wv,
                                                  _Float16* __restrict__ qw,
                                                  _Float16* __restrict__ kw,
                                                  _Float16* __restrict__ vt2,
                                                  unsigned* __restrict__ cnt) {
  __shared__ _Float16 wsl[24576];   // 48 KB: [mat2+half][kc][lane][j] f16
  const int tid = threadIdx.x;

  if (blockIdx.x == 0 && tid < 128) cnt[tid] = 0;   // visible to attn via dispatch boundary

  // Coalesced W load + swizzle into LDS. lgid layout (matches old prep_kernel):
  // lgid = (((mat*2+half)*8+kc)<<9) + (quad*16+n)*8 + j, with
  // e = kc*32+quad*8+j (emb idx), d = half*16+n (head-dim idx), src W[e*HD+d].
#pragma unroll
  for (int i = 0; i < 24; ++i) {
    const float* W = (i < 8) ? Wq : ((i < 16) ? Wk : Wv);
    int lu = (i & 7) * 1024 + tid * 4;      // flat idx within one matrix (float4 granular)
    float4 v4 = *(const float4*)(W + lu);
    int e = lu >> 5;                         // row (emb) index
    int d0 = lu & 31;                        // head-dim base (multiple of 4; same half)
    int kc = e >> 5, quad = (e >> 3) & 3, j = e & 7;
    int half = d0 >> 4;
    int n0 = d0 & 15;
    int mat = i >> 3;
    int base = (((mat * 2 + half) * 8 + kc) << 9) + (quad << 7) + j;
    float sc = (i < 8) ? L2E : 1.f;          // Wq pre-scaled: exp2-domain scores for free
    wsl[base + (n0 + 0) * 8] = (_Float16)(v4.x * sc);
    wsl[base + (n0 + 1) * 8] = (_Float16)(v4.y * sc);
    wsl[base + (n0 + 2) * 8] = (_Float16)(v4.z * sc);
    wsl[base + (n0 + 3) * 8] = (_Float16)(v4.w * sc);
  }
  __syncthreads();

  int lane = tid & 63, wave = tid >> 6;
  int n = lane & 15, quad = lane >> 4;
  int rowbase = blockIdx.x * 64 + wave * 16;

  floatx4 cq0 = {0,0,0,0}, cq1 = {0,0,0,0};
  floatx4 ck0 = {0,0,0,0}, ck1 = {0,0,0,0};
  floatx4 cv0 = {0,0,0,0}, cv1 = {0,0,0,0};

#pragma unroll
  for (int kc = 0; kc < 8; ++kc) {
    const float* xp = x + (size_t)(rowbase + n) * EMB + kc * 32 + quad * 8;
    float4 xa = *(const float4*)(xp);
    float4 xb = *(const float4*)(xp + 4);
    half8 a;
    a[0] = (_Float16)xa.x; a[1] = (_Float16)xa.y; a[2] = (_Float16)xa.z; a[3] = (_Float16)xa.w;
    a[4] = (_Float16)xb.x; a[5] = (_Float16)xb.y; a[6] = (_Float16)xb.z; a[7] = (_Float16)xb.w;
    const _Float16* wp = wsl + (kc << 9) + (lane << 3);
    half8 bq0 = *(const half8*)(wp);
    half8 bq1 = *(const half8*)(wp + (8  << 9));
    half8 bk0 = *(const half8*)(wp + (16 << 9));
    half8 bk1 = *(const half8*)(wp + (24 << 9));
    half8 bv0 = *(const half8*)(wp + (32 << 9));
    half8 bv1 = *(const half8*)(wp + (40 << 9));
    cq0 = __builtin_amdgcn_mfma_f32_16x16x32_f16(a, bq0, cq0, 0, 0, 0);
    cq1 = __builtin_amdgcn_mfma_f32_16x16x32_f16(a, bq1, cq1, 0, 0, 0);
    ck0 = __builtin_amdgcn_mfma_f32_16x16x32_f16(a, bk0, ck0, 0, 0, 0);
    ck1 = __builtin_amdgcn_mfma_f32_16x16x32_f16(a, bk1, ck1, 0, 0, 0);
    cv0 = __builtin_amdgcn_mfma_f32_16x16x32_f16(a, bv0, cv0, 0, 0, 0);
    cv1 = __builtin_amdgcn_mfma_f32_16x16x32_f16(a, bv1, cv1, 0, 0, 0);
  }

  int b = rowbase >> 12;
  int s0 = rowbase & (SEQ - 1);
  _Float16* vbase = vt2 + (size_t)b * SEQ * HD;
#pragma unroll
  for (int r = 0; r < 4; ++r) {
    int row = rowbase + quad * 4 + r;
    qw[row * HD + n]      = (_Float16)cq0[r];
    qw[row * HD + n + 16] = (_Float16)cq1[r];
    kw[row * HD + n]      = (_Float16)ck0[r];
    kw[row * HD + n + 16] = (_Float16)ck1[r];
    int s = s0 + quad * 4 + r;
    int blk = (s >> 3) << 8, sl = s & 7;   // key-block base (8 keys x 32 d), slot
    vbase[blk + n * 8 + sl]        = (_Float16)cv0[r];
    vbase[blk + (n + 16) * 8 + sl] = (_Float16)cv1[r];
  }
}

// ---------------- Kernel 2: flash attention + fused split-K combine (last-block fixup) ----
// 1024 blocks x 256 thr. Main loop identical to round-2 (verified). After storing its
// Op/M/L slice, each block ACQ_REL-increments cnt[qb]; the 8th arriver (release chain
// => all producers' data in LLC) merges the 8 splits for its 128 q-rows and writes out.
// No spinning, no residency assumption: safe under any dispatch order.
__global__ __launch_bounds__(256, 4) void attn_kernel(const _Float16* __restrict__ q,
                                                      const _Float16* __restrict__ k,
                                                      const _Float16* __restrict__ vt2,
                                                      _Float16* __restrict__ Op,
                                                      float* __restrict__ Mp,
                                                      float* __restrict__ Lp,
                                                      unsigned* __restrict__ cnt,
                                                      float* __restrict__ out) {
  const int t = threadIdx.x;
  const int w = t >> 6, lane = t & 63;
  const int n2 = lane & 31, h = lane >> 5;
  const int qb = blockIdx.x & 127;
  const int sp = blockIdx.x >> 7;
  const int b = qb >> 5;
  const int qrow0 = qb * 128 + w * 32;
  const int key0 = sp * KRANGE;

  const _Float16* kb = k   + (size_t)(b * SEQ + key0) * HD;
  const _Float16* vb = vt2 + (size_t)b * SEQ * HD + (size_t)key0 * HD;

  // Q^T B-frags (pre-scaled by L2E): B[k=d][n=qrow=n2]
  half8 qf0 = *(const half8*)(q + (qrow0 + n2) * HD + h * 8);
  half8 qf1 = *(const half8*)(q + (qrow0 + n2) * HD + 16 + h * 8);

  floatx16 o;
#pragma unroll
  for (int r = 0; r < 16; ++r) o[r] = 0.f;
  const floatx16 zero16 = o;
  float m = -__builtin_huge_valf();      // deferred reference max (exp2 domain)
  float mtrue = -__builtin_huge_valf();  // true running max (for epilogue rescale)
  float l = 0.f;

  // prefetch tile 0. V^T A-frag: A[m=d=n2][k=key=8h+j]
  half8 ka0 = *(const half8*)(kb + (size_t)n2 * HD + h * 8);
  half8 ka1 = *(const half8*)(kb + (size_t)n2 * HD + 16 + h * 8);
  half8 va0 = *(const half8*)(vb + h * 256 + n2 * 8);
  half8 va1 = *(const half8*)(vb + 512 + h * 256 + n2 * 8);

#pragma unroll 4
  for (int kt = 0; kt < NT; ++kt) {
    int nxt = (kt + 1) & (NT - 1);
    const _Float16* kn = kb + (size_t)(nxt * 32 + n2) * HD;
    const _Float16* vn = vb + nxt * 1024;
    half8 nka0 = *(const half8*)(kn + h * 8);
    half8 nka1 = *(const half8*)(kn + 16 + h * 8);
    half8 nva0 = *(const half8*)(vn + h * 256 + n2 * 8);
    half8 nva1 = *(const half8*)(vn + 512 + h * 256 + n2 * 8);

    // S^T tile [32 keys x 32 qrows]
    floatx16 s = __builtin_amdgcn_mfma_f32_32x32x16_f16(ka0, qf0, zero16, 0, 0, 0);
    s = __builtin_amdgcn_mfma_f32_32x32x16_f16(ka1, qf1, s, 0, 0, 0);

    floatx4 s0 = {s[0], s[1], s[2], s[3]};
    floatx4 s1 = {s[4], s[5], s[6], s[7]};
    floatx4 s2 = {s[8], s[9], s[10], s[11]};
    floatx4 s3 = {s[12], s[13], s[14], s[15]};
    floatx4 t01 = __builtin_elementwise_max(s0, s1);
    floatx4 t23 = __builtin_elementwise_max(s2, s3);
    floatx4 t4  = __builtin_elementwise_max(t01, t23);
    float mm = fmaxf(fmaxf(t4[0], t4[1]), fmaxf(t4[2], t4[3]));
    mm = fmaxf(mm, __shfl_xor(mm, 32));
    mtrue = fmaxf(mtrue, mm);

    // defer-max: only rescale when some row's max grew past THR (wave-uniform branch)
    if (__any(mm > m + DEFER_THR)) {
      float mnew = fmaxf(m, mm);
      float alpha = __builtin_amdgcn_exp2f(m - mnew);
      m = mnew;
#pragma unroll
      for (int r = 0; r < 16; ++r) o[r] *= alpha;
      l *= alpha;
    }

    // p = exp2(s - m) <= 2^THR, pack consecutive-key pairs
    unsigned pk[8];
#pragma unroll
    for (int g = 0; g < 8; ++g) {
      float p0 = __builtin_amdgcn_exp2f(s[2 * g] - m);
      float p1 = __builtin_amdgcn_exp2f(s[2 * g + 1] - m);
      pk[g] = __builtin_bit_cast(unsigned, __builtin_amdgcn_cvt_pkrtz(p0, p1));
    }

    // l partial: own 16 keys via f16 dot2 (partner merged once after the loop)
    float lA = sum2(pk[3], sum2(pk[2], sum2(pk[1], sum2(pk[0], 0.f))));
    float lB = sum2(pk[7], sum2(pk[6], sum2(pk[5], sum2(pk[4], 0.f))));
    l += lA + lB;

    // P^T B-frags via permlane32_swap
    unsigned b00 = pk[0], b02 = pk[2]; plswap(b00, b02);
    unsigned b01 = pk[1], b03 = pk[3]; plswap(b01, b03);
    unsigned b10 = pk[4], b12 = pk[6]; plswap(b10, b12);
    unsigned b11 = pk[5], b13 = pk[7]; plswap(b11, b13);

    // O^T += V^T · P^T  (two key halves)
    o = __builtin_amdgcn_mfma_f32_32x32x16_f16(va0, mk8(b00, b01, b02, b03), o, 0, 0, 0);
    o = __builtin_amdgcn_mfma_f32_32x32x16_f16(va1, mk8(b10, b11, b12, b13), o, 0, 0, 0);

    ka0 = nka0; ka1 = nka1; va0 = nva0; va1 = nva1;
  }

  // epilogue: rescale to the true max so f16 Op cannot overflow (p_eff <= 1)
  float scale = __builtin_amdgcn_exp2f(m - mtrue);
  l *= scale;
  l = l + __shfl_xor(l, 32);

  size_t obase = ((size_t)(sp * NQROW + qrow0) + n2) * 32;
#pragma unroll
  for (int bb = 0; bb < 4; ++bb) {
    half4v pv;
    pv[0] = (_Float16)(o[4 * bb + 0] * scale);
    pv[1] = (_Float16)(o[4 * bb + 1] * scale);
    pv[2] = (_Float16)(o[4 * bb + 2] * scale);
    pv[3] = (_Float16)(o[4 * bb + 3] * scale);
    *(half4v*)&Op[obase + 8 * bb + 4 * h] = pv;
  }
  if (h == 0) {
    int mi = sp * NQROW + qrow0 + n2;
    Mp[mi] = mtrue;
    Lp[mi] = l;
  }

  // ---- fused split-K combine: last block per qb merges the 8 splits ----
  __shared__ int lastflag;
  __syncthreads();   // all 4 waves' Op/M/L stores issued (vmcnt drained at barrier)
  if (t == 0) {
    unsigned old = __hip_atomic_fetch_add(&cnt[qb], 1u, __ATOMIC_ACQ_REL,
                                          __HIP_MEMORY_SCOPE_AGENT);
    lastflag = (old == NSPLIT - 1u);
  }
  __syncthreads();
  if (lastflag) {
    __threadfence();   // acquire for all reading threads (L1/L2 inv)
#pragma unroll
    for (int it = 0; it < 4; ++it) {
      int item = it * 256 + t;            // 128 rows x 8 d-chunks = 1024 items
      int qrow = qb * 128 + (item >> 3);
      int dc = item & 7;
      float mv[NSPLIT];
      float ms = -__builtin_huge_valf();
#pragma unroll
      for (int sp2 = 0; sp2 < NSPLIT; ++sp2) {
        mv[sp2] = Mp[sp2 * NQROW + qrow];
        ms = fmaxf(ms, mv[sp2]);
      }
      float L = 0.f;
      floatx4 O = {0.f, 0.f, 0.f, 0.f};
#pragma unroll
      for (int sp2 = 0; sp2 < NSPLIT; ++sp2) {
        float ww = __builtin_amdgcn_exp2f(mv[sp2] - ms);
        L += ww * Lp[sp2 * NQROW + qrow];
        half4v ov = *(const half4v*)&Op[((size_t)(sp2 * NQROW + qrow)) * 32 + dc * 4];
#pragma unroll
        for (int r = 0; r < 4; ++r) O[r] += ww * (float)ov[r];
      }
      float inv = SCALING / L;
      floatx4 res = {O[0] * inv, O[1] * inv, O[2] * inv, O[3] * inv};
      *(floatx4*)&out[qrow * HD + dc * 4] = res;
    }
  }
}

extern "C" void kernel_launch(void* const* d_in, const int* in_sizes, int n_in,
                              void* d_out, int out_size, void* d_ws, size_t ws_size,
                              hipStream_t stream) {
  const float* x  = (const float*)d_in[0];
  const float* Wq = (const float*)d_in[1];
  const float* Wk = (const float*)d_in[2];
  const float* Wv = (const float*)d_in[3];
  float* out = (float*)d_out;

  _Float16* qw  = (_Float16*)d_ws;          // [16384][32]
  _Float16* kw  = qw + NQROW * HD;          // [16384][32]
  _Float16* vt2 = kw + NQROW * HD;          // [4][512][32][8] key-tiled V
  _Float16* Op  = vt2 + NQROW * HD;         // [8][16384][32] f16 (8 MB)
  float* Mp = (float*)(Op + (size_t)NSPLIT * NQROW * 32);  // [8][16384]
  float* Lp = Mp + NSPLIT * NQROW;                         // [8][16384]
  unsigned* cnt = (unsigned*)(Lp + NSPLIT * NQROW);        // [128] split-K counters

  qkv_kernel<<<256, 256, 0, stream>>>(x, Wq, Wk, Wv, qw, kw, vt2, cnt);
  attn_kernel<<<1024, 256, 0, stream>>>(qw, kw, vt2, Op, Mp, Lp, cnt, out);
}

// Round 6
// 95.957 us; speedup vs baseline: 5.3412x; 1.4835x over previous
//
#include <hip/hip_runtime.h>

#define EMB 256
#define HD 32
#define SEQ 4096
#define NSPLIT 8      // key splits across blocks
#define KRANGE 512    // keys per block (shared by its 4 waves)
#define NT (KRANGE / 32)
#define NQROW 16384   // B*S

typedef _Float16 half8 __attribute__((ext_vector_type(8)));
typedef _Float16 half4v __attribute__((ext_vector_type(4)));
typedef _Float16 half2v __attribute__((ext_vector_type(2)));
typedef float floatx4 __attribute__((ext_vector_type(4)));
typedef float floatx16 __attribute__((ext_vector_type(16)));
typedef unsigned uint2v __attribute__((ext_vector_type(2)));

#define L2E 1.44269504088896340736f
#define SCALING 0.17677669529663687f   // 32^-0.5, applied POST-softmax
#define DEFER_THR 8.0f                 // exp2-domain defer-max threshold: p <= 2^8

__device__ __forceinline__ half8 mk8(unsigned a, unsigned b, unsigned c, unsigned d) {
  union { unsigned u[4]; half8 h; } z;
  z.u[0] = a; z.u[1] = b; z.u[2] = c; z.u[3] = d;
  return z.h;
}

// permlane32_swap semantics: a' = {a.lo, b.lo}, b' = {a.hi, b.hi}
__device__ __forceinline__ void plswap(unsigned& a, unsigned& b) {
#if __has_builtin(__builtin_amdgcn_permlane32_swap)
  uint2v r = __builtin_amdgcn_permlane32_swap(a, b, false, false);
  a = r[0]; b = r[1];
#else
  unsigned sa = (unsigned)__shfl_xor((int)a, 32);
  unsigned sb = (unsigned)__shfl_xor((int)b, 32);
  bool hi = (threadIdx.x & 32) != 0;
  unsigned na = hi ? sb : a;
  unsigned nb = hi ? b : sa;
  a = na; b = nb;
#endif
}

// sum of the two f16 halves of pk into acc (consistent with the f16 P fed to PV MFMA)
__device__ __forceinline__ float sum2(unsigned pk, float acc) {
  half2v a = __builtin_bit_cast(half2v, pk);
#if __has_builtin(__builtin_amdgcn_fdot2)
  half2v one; one[0] = (_Float16)1.f; one[1] = (_Float16)1.f;
  return __builtin_amdgcn_fdot2(a, one, acc, false);
#else
  return acc + (float)a[0] + (float)a[1];
#endif
}

// ---------------- Kernel 1: fused W-swizzle (LDS) + QKV projection (round-5 verified) -------
__global__ __launch_bounds__(256) void qkv_kernel(const float* __restrict__ x,
                                                  const float* __restrict__ Wq,
                                                  const float* __restrict__ Wk,
                                                  const float* __restrict__ Wv,
                                                  _Float16* __restrict__ qw,
                                                  _Float16* __restrict__ kw,
                                                  _Float16* __restrict__ vt2) {
  __shared__ _Float16 wsl[24576];   // 48 KB: [mat2+half][kc][lane][j] f16
  const int tid = threadIdx.x;

  // Coalesced W load + swizzle into LDS (B-frag order); Wq pre-scaled by L2E.
#pragma unroll
  for (int i = 0; i < 24; ++i) {
    const float* W = (i < 8) ? Wq : ((i < 16) ? Wk : Wv);
    int lu = (i & 7) * 1024 + tid * 4;
    float4 v4 = *(const float4*)(W + lu);
    int e = lu >> 5;
    int d0 = lu & 31;
    int kc = e >> 5, quad = (e >> 3) & 3, j = e & 7;
    int half = d0 >> 4;
    int n0 = d0 & 15;
    int mat = i >> 3;
    int base = (((mat * 2 + half) * 8 + kc) << 9) + (quad << 7) + j;
    float sc = (i < 8) ? L2E : 1.f;
    wsl[base + (n0 + 0) * 8] = (_Float16)(v4.x * sc);
    wsl[base + (n0 + 1) * 8] = (_Float16)(v4.y * sc);
    wsl[base + (n0 + 2) * 8] = (_Float16)(v4.z * sc);
    wsl[base + (n0 + 3) * 8] = (_Float16)(v4.w * sc);
  }
  __syncthreads();

  int lane = tid & 63, wave = tid >> 6;
  int n = lane & 15, quad = lane >> 4;
  int rowbase = blockIdx.x * 64 + wave * 16;

  floatx4 cq0 = {0,0,0,0}, cq1 = {0,0,0,0};
  floatx4 ck0 = {0,0,0,0}, ck1 = {0,0,0,0};
  floatx4 cv0 = {0,0,0,0}, cv1 = {0,0,0,0};

#pragma unroll
  for (int kc = 0; kc < 8; ++kc) {
    const float* xp = x + (size_t)(rowbase + n) * EMB + kc * 32 + quad * 8;
    float4 xa = *(const float4*)(xp);
    float4 xb = *(const float4*)(xp + 4);
    half8 a;
    a[0] = (_Float16)xa.x; a[1] = (_Float16)xa.y; a[2] = (_Float16)xa.z; a[3] = (_Float16)xa.w;
    a[4] = (_Float16)xb.x; a[5] = (_Float16)xb.y; a[6] = (_Float16)xb.z; a[7] = (_Float16)xb.w;
    const _Float16* wp = wsl + (kc << 9) + (lane << 3);
    half8 bq0 = *(const half8*)(wp);
    half8 bq1 = *(const half8*)(wp + (8  << 9));
    half8 bk0 = *(const half8*)(wp + (16 << 9));
    half8 bk1 = *(const half8*)(wp + (24 << 9));
    half8 bv0 = *(const half8*)(wp + (32 << 9));
    half8 bv1 = *(const half8*)(wp + (40 << 9));
    cq0 = __builtin_amdgcn_mfma_f32_16x16x32_f16(a, bq0, cq0, 0, 0, 0);
    cq1 = __builtin_amdgcn_mfma_f32_16x16x32_f16(a, bq1, cq1, 0, 0, 0);
    ck0 = __builtin_amdgcn_mfma_f32_16x16x32_f16(a, bk0, ck0, 0, 0, 0);
    ck1 = __builtin_amdgcn_mfma_f32_16x16x32_f16(a, bk1, ck1, 0, 0, 0);
    cv0 = __builtin_amdgcn_mfma_f32_16x16x32_f16(a, bv0, cv0, 0, 0, 0);
    cv1 = __builtin_amdgcn_mfma_f32_16x16x32_f16(a, bv1, cv1, 0, 0, 0);
  }

  int b = rowbase >> 12;
  int s0 = rowbase & (SEQ - 1);
  _Float16* vbase = vt2 + (size_t)b * SEQ * HD;
#pragma unroll
  for (int r = 0; r < 4; ++r) {
    int row = rowbase + quad * 4 + r;
    qw[row * HD + n]      = (_Float16)cq0[r];
    qw[row * HD + n + 16] = (_Float16)cq1[r];
    kw[row * HD + n]      = (_Float16)ck0[r];
    kw[row * HD + n + 16] = (_Float16)ck1[r];
    int s = s0 + quad * 4 + r;
    int blk = (s >> 3) << 8, sl = s & 7;   // key-block base (8 keys x 32 d), slot
    vbase[blk + n * 8 + sl]        = (_Float16)cv0[r];
    vbase[blk + (n + 16) * 8 + sl] = (_Float16)cv1[r];
  }
}

// ---------------- Kernel 2: flash attention, depth-2 prefetch pipeline, NO atomics ---------
// 1024 blocks x 256 thr = 4 blocks/CU, 16 waves/CU. Tiles kt+2/kt+3 issued while
// computing kt/kt+1: ~2 iterations (~700-1000 cyc) of load slack covers HBM/LLC
// latency on first-touch K/V. Fully unrolled so all frag regs are statically indexed.
__global__ __launch_bounds__(256, 4) void attn_kernel(const _Float16* __restrict__ q,
                                                      const _Float16* __restrict__ k,
                                                      const _Float16* __restrict__ vt2,
                                                      _Float16* __restrict__ Op,
                                                      float* __restrict__ Mp,
                                                      float* __restrict__ Lp) {
  const int t = threadIdx.x;
  const int w = t >> 6, lane = t & 63;
  const int n2 = lane & 31, h = lane >> 5;
  const int qb = blockIdx.x & 127;
  const int sp = blockIdx.x >> 7;
  const int b = qb >> 5;
  const int qrow0 = qb * 128 + w * 32;
  const int key0 = sp * KRANGE;

  const _Float16* kb = k   + (size_t)(b * SEQ + key0) * HD;
  const _Float16* vb = vt2 + (size_t)b * SEQ * HD + (size_t)key0 * HD;

  // Q^T B-frags (pre-scaled by L2E): B[k=d][n=qrow=n2]
  half8 qf0 = *(const half8*)(q + (qrow0 + n2) * HD + h * 8);
  half8 qf1 = *(const half8*)(q + (qrow0 + n2) * HD + 16 + h * 8);

  floatx16 o;
#pragma unroll
  for (int r = 0; r < 16; ++r) o[r] = 0.f;
  const floatx16 zero16 = o;
  float m = -__builtin_huge_valf();      // deferred reference max (exp2 domain)
  float mtrue = -__builtin_huge_valf();  // true running max (for epilogue rescale)
  float l = 0.f;

  auto ldt = [&](int tile, half8& k0, half8& k1, half8& v0, half8& v1) {
    const _Float16* kn = kb + (size_t)(tile * 32 + n2) * HD;
    const _Float16* vn = vb + tile * 1024;
    k0 = *(const half8*)(kn + h * 8);
    k1 = *(const half8*)(kn + 16 + h * 8);
    v0 = *(const half8*)(vn + h * 256 + n2 * 8);
    v1 = *(const half8*)(vn + 512 + h * 256 + n2 * 8);
  };

  auto tilecomp = [&](half8 tka0, half8 tka1, half8 tva0, half8 tva1) {
    // S^T tile [32 keys x 32 qrows]
    floatx16 s = __builtin_amdgcn_mfma_f32_32x32x16_f16(tka0, qf0, zero16, 0, 0, 0);
    s = __builtin_amdgcn_mfma_f32_32x32x16_f16(tka1, qf1, s, 0, 0, 0);

    floatx4 s0 = {s[0], s[1], s[2], s[3]};
    floatx4 s1 = {s[4], s[5], s[6], s[7]};
    floatx4 s2 = {s[8], s[9], s[10], s[11]};
    floatx4 s3 = {s[12], s[13], s[14], s[15]};
    floatx4 t01 = __builtin_elementwise_max(s0, s1);
    floatx4 t23 = __builtin_elementwise_max(s2, s3);
    floatx4 t4  = __builtin_elementwise_max(t01, t23);
    float mm = fmaxf(fmaxf(t4[0], t4[1]), fmaxf(t4[2], t4[3]));
    mm = fmaxf(mm, __shfl_xor(mm, 32));
    mtrue = fmaxf(mtrue, mm);

    // defer-max: only rescale when some row's max grew past THR (wave-uniform branch)
    if (__any(mm > m + DEFER_THR)) {
      float mnew = fmaxf(m, mm);
      float alpha = __builtin_amdgcn_exp2f(m - mnew);
      m = mnew;
#pragma unroll
      for (int r = 0; r < 16; ++r) o[r] *= alpha;
      l *= alpha;
    }

    // p = exp2(s - m) <= 2^THR, pack consecutive-key pairs
    unsigned pk[8];
#pragma unroll
    for (int g = 0; g < 8; ++g) {
      float p0 = __builtin_amdgcn_exp2f(s[2 * g] - m);
      float p1 = __builtin_amdgcn_exp2f(s[2 * g + 1] - m);
      pk[g] = __builtin_bit_cast(unsigned, __builtin_amdgcn_cvt_pkrtz(p0, p1));
    }

    // l partial: own 16 keys via f16 dot2 (partner merged once after the loop)
    float lA = sum2(pk[3], sum2(pk[2], sum2(pk[1], sum2(pk[0], 0.f))));
    float lB = sum2(pk[7], sum2(pk[6], sum2(pk[5], sum2(pk[4], 0.f))));
    l += lA + lB;

    // P^T B-frags via permlane32_swap
    unsigned b00 = pk[0], b02 = pk[2]; plswap(b00, b02);
    unsigned b01 = pk[1], b03 = pk[3]; plswap(b01, b03);
    unsigned b10 = pk[4], b12 = pk[6]; plswap(b10, b12);
    unsigned b11 = pk[5], b13 = pk[7]; plswap(b11, b13);

    // O^T += V^T · P^T  (two key halves)
    o = __builtin_amdgcn_mfma_f32_32x32x16_f16(tva0, mk8(b00, b01, b02, b03), o, 0, 0, 0);
    o = __builtin_amdgcn_mfma_f32_32x32x16_f16(tva1, mk8(b10, b11, b12, b13), o, 0, 0, 0);
  };

  // depth-2 pipeline: preload tiles 0 and 1; in body kt, issue kt+2 / kt+3.
  half8 ak0, ak1, av0, av1, bk0, bk1, bv0, bv1;
  ldt(0, ak0, ak1, av0, av1);
  ldt(1, bk0, bk1, bv0, bv1);

#pragma unroll
  for (int kt = 0; kt < NT; kt += 2) {
    half8 ck0, ck1, cv0, cv1, dk0, dk1, dv0, dv1;
    ldt((kt + 2) & (NT - 1), ck0, ck1, cv0, cv1);   // wrap: harmless reload on tail
    tilecomp(ak0, ak1, av0, av1);
    ldt((kt + 3) & (NT - 1), dk0, dk1, dv0, dv1);
    tilecomp(bk0, bk1, bv0, bv1);
    ak0 = ck0; ak1 = ck1; av0 = cv0; av1 = cv1;
    bk0 = dk0; bk1 = dk1; bv0 = dv0; bv1 = dv1;
  }

  // epilogue: rescale to the true max so f16 Op cannot overflow (p_eff <= 1)
  float scale = __builtin_amdgcn_exp2f(m - mtrue);
  l *= scale;
  l = l + __shfl_xor(l, 32);

  size_t obase = ((size_t)(sp * NQROW + qrow0) + n2) * 32;
#pragma unroll
  for (int bb = 0; bb < 4; ++bb) {
    half4v pv;
    pv[0] = (_Float16)(o[4 * bb + 0] * scale);
    pv[1] = (_Float16)(o[4 * bb + 1] * scale);
    pv[2] = (_Float16)(o[4 * bb + 2] * scale);
    pv[3] = (_Float16)(o[4 * bb + 3] * scale);
    *(half4v*)&Op[obase + 8 * bb + 4 * h] = pv;
  }
  if (h == 0) {
    int mi = sp * NQROW + qrow0 + n2;
    Mp[mi] = mtrue;
    Lp[mi] = l;
  }
}

// ---------------- Kernel 3: merge the 8 key-splits, normalize, scale (round-2 verified) ----
__global__ __launch_bounds__(256) void combine_kernel(const _Float16* __restrict__ Op,
                                                      const float* __restrict__ Mp,
                                                      const float* __restrict__ Lp,
                                                      float* __restrict__ out) {
  int gid = blockIdx.x * 256 + threadIdx.x;   // [0, 131072)
  int dc = gid & 7, qrow = gid >> 3;
  float mv[NSPLIT];
  float ms = -__builtin_huge_valf();
#pragma unroll
  for (int sp = 0; sp < NSPLIT; ++sp) {
    mv[sp] = Mp[sp * NQROW + qrow];
    ms = fmaxf(ms, mv[sp]);
  }
  float L = 0.f;
  floatx4 O = {0.f, 0.f, 0.f, 0.f};
#pragma unroll
  for (int sp = 0; sp < NSPLIT; ++sp) {
    float ww = __builtin_amdgcn_exp2f(mv[sp] - ms);
    L += ww * Lp[sp * NQROW + qrow];
    half4v ov = *(const half4v*)&Op[((size_t)(sp * NQROW + qrow)) * 32 + dc * 4];
#pragma unroll
    for (int r = 0; r < 4; ++r) O[r] += ww * (float)ov[r];
  }
  float inv = SCALING / L;
  floatx4 res = {O[0] * inv, O[1] * inv, O[2] * inv, O[3] * inv};
  *(floatx4*)&out[qrow * HD + dc * 4] = res;
}

extern "C" void kernel_launch(void* const* d_in, const int* in_sizes, int n_in,
                              void* d_out, int out_size, void* d_ws, size_t ws_size,
                              hipStream_t stream) {
  const float* x  = (const float*)d_in[0];
  const float* Wq = (const float*)d_in[1];
  const float* Wk = (const float*)d_in[2];
  const float* Wv = (const float*)d_in[3];
  float* out = (float*)d_out;

  _Float16* qw  = (_Float16*)d_ws;          // [16384][32]
  _Float16* kw  = qw + NQROW * HD;          // [16384][32]
  _Float16* vt2 = kw + NQROW * HD;          // [4][512][32][8] key-tiled V
  _Float16* Op  = vt2 + NQROW * HD;         // [8][16384][32] f16 (8 MB)
  float* Mp = (float*)(Op + (size_t)NSPLIT * NQROW * 32);  // [8][16384]
  float* Lp = Mp + NSPLIT * NQROW;                         // [8][16384]

  qkv_kernel<<<256, 256, 0, stream>>>(x, Wq, Wk, Wv, qw, kw, vt2);
  attn_kernel<<<1024, 256, 0, stream>>>(qw, kw, vt2, Op, Mp, Lp);
  combine_kernel<<<512, 256, 0, stream>>>(Op, Mp, Lp, out);
}

// Round 7
// 93.196 us; speedup vs baseline: 5.4995x; 1.0296x over previous
//
#include <hip/hip_runtime.h>

#define EMB 256
#define HD 32
#define SEQ 4096
#define NSPLIT 8      // key splits = waves per attn block (merged in LDS, no global round-trip)
#define KRANGE 512    // keys per wave
#define NT (KRANGE / 32)
#define NQROW 16384   // B*S

typedef _Float16 half8 __attribute__((ext_vector_type(8)));
typedef _Float16 half4v __attribute__((ext_vector_type(4)));
typedef _Float16 half2v __attribute__((ext_vector_type(2)));
typedef float floatx4 __attribute__((ext_vector_type(4)));
typedef float floatx16 __attribute__((ext_vector_type(16)));
typedef unsigned uint2v __attribute__((ext_vector_type(2)));

#define L2E 1.44269504088896340736f
#define SCALING 0.17677669529663687f   // 32^-0.5, applied POST-softmax
#define DEFER_THR 8.0f                 // exp2-domain defer-max threshold: p <= 2^8

__device__ __forceinline__ half8 mk8(unsigned a, unsigned b, unsigned c, unsigned d) {
  union { unsigned u[4]; half8 h; } z;
  z.u[0] = a; z.u[1] = b; z.u[2] = c; z.u[3] = d;
  return z.h;
}

// permlane32_swap semantics: a' = {a.lo, b.lo}, b' = {a.hi, b.hi}
__device__ __forceinline__ void plswap(unsigned& a, unsigned& b) {
#if __has_builtin(__builtin_amdgcn_permlane32_swap)
  uint2v r = __builtin_amdgcn_permlane32_swap(a, b, false, false);
  a = r[0]; b = r[1];
#else
  unsigned sa = (unsigned)__shfl_xor((int)a, 32);
  unsigned sb = (unsigned)__shfl_xor((int)b, 32);
  bool hi = (threadIdx.x & 32) != 0;
  unsigned na = hi ? sb : a;
  unsigned nb = hi ? b : sa;
  a = na; b = nb;
#endif
}

// sum of the two f16 halves of pk into acc (consistent with the f16 P fed to PV MFMA)
__device__ __forceinline__ float sum2(unsigned pk, float acc) {
  half2v a = __builtin_bit_cast(half2v, pk);
#if __has_builtin(__builtin_amdgcn_fdot2)
  half2v one; one[0] = (_Float16)1.f; one[1] = (_Float16)1.f;
  return __builtin_amdgcn_fdot2(a, one, acc, false);
#else
  return acc + (float)a[0] + (float)a[1];
#endif
}

// ---------------- Kernel 1: fused W-swizzle (LDS) + QKV projection (round-6 verified) -------
__global__ __launch_bounds__(256) void qkv_kernel(const float* __restrict__ x,
                                                  const float* __restrict__ Wq,
                                                  const float* __restrict__ Wk,
                                                  const float* __restrict__ Wv,
                                                  _Float16* __restrict__ qw,
                                                  _Float16* __restrict__ kw,
                                                  _Float16* __restrict__ vt2) {
  __shared__ _Float16 wsl[24576];   // 48 KB: [mat2+half][kc][lane][j] f16
  const int tid = threadIdx.x;

  // Coalesced W load + swizzle into LDS (B-frag order); Wq pre-scaled by L2E.
#pragma unroll
  for (int i = 0; i < 24; ++i) {
    const float* W = (i < 8) ? Wq : ((i < 16) ? Wk : Wv);
    int lu = (i & 7) * 1024 + tid * 4;
    float4 v4 = *(const float4*)(W + lu);
    int e = lu >> 5;
    int d0 = lu & 31;
    int kc = e >> 5, quad = (e >> 3) & 3, j = e & 7;
    int half = d0 >> 4;
    int n0 = d0 & 15;
    int mat = i >> 3;
    int base = (((mat * 2 + half) * 8 + kc) << 9) + (quad << 7) + j;
    float sc = (i < 8) ? L2E : 1.f;
    wsl[base + (n0 + 0) * 8] = (_Float16)(v4.x * sc);
    wsl[base + (n0 + 1) * 8] = (_Float16)(v4.y * sc);
    wsl[base + (n0 + 2) * 8] = (_Float16)(v4.z * sc);
    wsl[base + (n0 + 3) * 8] = (_Float16)(v4.w * sc);
  }
  __syncthreads();

  int lane = tid & 63, wave = tid >> 6;
  int n = lane & 15, quad = lane >> 4;
  int rowbase = blockIdx.x * 64 + wave * 16;

  floatx4 cq0 = {0,0,0,0}, cq1 = {0,0,0,0};
  floatx4 ck0 = {0,0,0,0}, ck1 = {0,0,0,0};
  floatx4 cv0 = {0,0,0,0}, cv1 = {0,0,0,0};

#pragma unroll
  for (int kc = 0; kc < 8; ++kc) {
    const float* xp = x + (size_t)(rowbase + n) * EMB + kc * 32 + quad * 8;
    float4 xa = *(const float4*)(xp);
    float4 xb = *(const float4*)(xp + 4);
    half8 a;
    a[0] = (_Float16)xa.x; a[1] = (_Float16)xa.y; a[2] = (_Float16)xa.z; a[3] = (_Float16)xa.w;
    a[4] = (_Float16)xb.x; a[5] = (_Float16)xb.y; a[6] = (_Float16)xb.z; a[7] = (_Float16)xb.w;
    const _Float16* wp = wsl + (kc << 9) + (lane << 3);
    half8 bq0 = *(const half8*)(wp);
    half8 bq1 = *(const half8*)(wp + (8  << 9));
    half8 bk0 = *(const half8*)(wp + (16 << 9));
    half8 bk1 = *(const half8*)(wp + (24 << 9));
    half8 bv0 = *(const half8*)(wp + (32 << 9));
    half8 bv1 = *(const half8*)(wp + (40 << 9));
    cq0 = __builtin_amdgcn_mfma_f32_16x16x32_f16(a, bq0, cq0, 0, 0, 0);
    cq1 = __builtin_amdgcn_mfma_f32_16x16x32_f16(a, bq1, cq1, 0, 0, 0);
    ck0 = __builtin_amdgcn_mfma_f32_16x16x32_f16(a, bk0, ck0, 0, 0, 0);
    ck1 = __builtin_amdgcn_mfma_f32_16x16x32_f16(a, bk1, ck1, 0, 0, 0);
    cv0 = __builtin_amdgcn_mfma_f32_16x16x32_f16(a, bv0, cv0, 0, 0, 0);
    cv1 = __builtin_amdgcn_mfma_f32_16x16x32_f16(a, bv1, cv1, 0, 0, 0);
  }

  int b = rowbase >> 12;
  int s0 = rowbase & (SEQ - 1);
  _Float16* vbase = vt2 + (size_t)b * SEQ * HD;
#pragma unroll
  for (int r = 0; r < 4; ++r) {
    int row = rowbase + quad * 4 + r;
    qw[row * HD + n]      = (_Float16)cq0[r];
    qw[row * HD + n + 16] = (_Float16)cq1[r];
    kw[row * HD + n]      = (_Float16)ck0[r];
    kw[row * HD + n + 16] = (_Float16)ck1[r];
    int s = s0 + quad * 4 + r;
    int blk = (s >> 3) << 8, sl = s & 7;   // key-block base (8 keys x 32 d), slot
    vbase[blk + n * 8 + sl]        = (_Float16)cv0[r];
    vbase[blk + (n + 16) * 8 + sl] = (_Float16)cv1[r];
  }
}

// ---------------- Kernel 2: flash attention + in-block LDS split-K merge -------------------
// 512 blocks x 512 thr (8 waves) = 2 blocks/CU, 16 waves/CU. Block owns 32 q-rows;
// wave w handles key-split sp=w (512 keys, 16 tiles — main loop byte-identical to the
// verified round-6 body). The 8 splits merge via __syncthreads + LDS (f32): no Op/M/L
// global round-trip, no combine dispatch, no device-scope sync.
__global__ __launch_bounds__(512, 4) void attn_kernel(const _Float16* __restrict__ q,
                                                      const _Float16* __restrict__ k,
                                                      const _Float16* __restrict__ vt2,
                                                      float* __restrict__ out) {
  // sO stride 36 words: pads row to break the d-column bank alignment (reads 2 lanes/bank).
  __shared__ float sO[NSPLIT * 32 * 36];   // 36 KB
  __shared__ float sM[NSPLIT * 32];
  __shared__ float sL[NSPLIT * 32];

  const int t = threadIdx.x;
  const int w = t >> 6, lane = t & 63;     // w = wave = key-split
  const int n2 = lane & 31, h = lane >> 5;
  const int qrow0 = blockIdx.x * 32;
  const int b = qrow0 >> 12;
  const int key0 = w * KRANGE;

  const _Float16* kb = k   + (size_t)(b * SEQ + key0) * HD;
  const _Float16* vb = vt2 + (size_t)b * SEQ * HD + (size_t)key0 * HD;

  // Q^T B-frags (pre-scaled by L2E): B[k=d][n=qrow=n2]
  half8 qf0 = *(const half8*)(q + (qrow0 + n2) * HD + h * 8);
  half8 qf1 = *(const half8*)(q + (qrow0 + n2) * HD + 16 + h * 8);

  floatx16 o;
#pragma unroll
  for (int r = 0; r < 16; ++r) o[r] = 0.f;
  const floatx16 zero16 = o;
  float m = -__builtin_huge_valf();      // deferred reference max (exp2 domain)
  float mtrue = -__builtin_huge_valf();  // true running max (for epilogue rescale)
  float l = 0.f;

  auto ldt = [&](int tile, half8& k0, half8& k1, half8& v0, half8& v1) {
    const _Float16* kn = kb + (size_t)(tile * 32 + n2) * HD;
    const _Float16* vn = vb + tile * 1024;
    k0 = *(const half8*)(kn + h * 8);
    k1 = *(const half8*)(kn + 16 + h * 8);
    v0 = *(const half8*)(vn + h * 256 + n2 * 8);
    v1 = *(const half8*)(vn + 512 + h * 256 + n2 * 8);
  };

  auto tilecomp = [&](half8 tka0, half8 tka1, half8 tva0, half8 tva1) {
    // S^T tile [32 keys x 32 qrows]
    floatx16 s = __builtin_amdgcn_mfma_f32_32x32x16_f16(tka0, qf0, zero16, 0, 0, 0);
    s = __builtin_amdgcn_mfma_f32_32x32x16_f16(tka1, qf1, s, 0, 0, 0);

    floatx4 s0 = {s[0], s[1], s[2], s[3]};
    floatx4 s1 = {s[4], s[5], s[6], s[7]};
    floatx4 s2 = {s[8], s[9], s[10], s[11]};
    floatx4 s3 = {s[12], s[13], s[14], s[15]};
    floatx4 t01 = __builtin_elementwise_max(s0, s1);
    floatx4 t23 = __builtin_elementwise_max(s2, s3);
    floatx4 t4  = __builtin_elementwise_max(t01, t23);
    float mm = fmaxf(fmaxf(t4[0], t4[1]), fmaxf(t4[2], t4[3]));
    mm = fmaxf(mm, __shfl_xor(mm, 32));
    mtrue = fmaxf(mtrue, mm);

    // defer-max: only rescale when some row's max grew past THR (wave-uniform branch)
    if (__any(mm > m + DEFER_THR)) {
      float mnew = fmaxf(m, mm);
      float alpha = __builtin_amdgcn_exp2f(m - mnew);
      m = mnew;
#pragma unroll
      for (int r = 0; r < 16; ++r) o[r] *= alpha;
      l *= alpha;
    }

    // p = exp2(s - m) <= 2^THR, pack consecutive-key pairs
    unsigned pk[8];
#pragma unroll
    for (int g = 0; g < 8; ++g) {
      float p0 = __builtin_amdgcn_exp2f(s[2 * g] - m);
      float p1 = __builtin_amdgcn_exp2f(s[2 * g + 1] - m);
      pk[g] = __builtin_bit_cast(unsigned, __builtin_amdgcn_cvt_pkrtz(p0, p1));
    }

    // l partial: own 16 keys via f16 dot2 (partner merged once after the loop)
    float lA = sum2(pk[3], sum2(pk[2], sum2(pk[1], sum2(pk[0], 0.f))));
    float lB = sum2(pk[7], sum2(pk[6], sum2(pk[5], sum2(pk[4], 0.f))));
    l += lA + lB;

    // P^T B-frags via permlane32_swap
    unsigned b00 = pk[0], b02 = pk[2]; plswap(b00, b02);
    unsigned b01 = pk[1], b03 = pk[3]; plswap(b01, b03);
    unsigned b10 = pk[4], b12 = pk[6]; plswap(b10, b12);
    unsigned b11 = pk[5], b13 = pk[7]; plswap(b11, b13);

    // O^T += V^T · P^T  (two key halves)
    o = __builtin_amdgcn_mfma_f32_32x32x16_f16(tva0, mk8(b00, b01, b02, b03), o, 0, 0, 0);
    o = __builtin_amdgcn_mfma_f32_32x32x16_f16(tva1, mk8(b10, b11, b12, b13), o, 0, 0, 0);
  };

  // depth-2 pipeline: preload tiles 0 and 1; in body kt, issue kt+2 / kt+3.
  half8 ak0, ak1, av0, av1, bk0, bk1, bv0, bv1;
  ldt(0, ak0, ak1, av0, av1);
  ldt(1, bk0, bk1, bv0, bv1);

#pragma unroll
  for (int kt = 0; kt < NT; kt += 2) {
    half8 ck0, ck1, cv0, cv1, dk0, dk1, dv0, dv1;
    ldt((kt + 2) & (NT - 1), ck0, ck1, cv0, cv1);   // wrap: harmless reload on tail
    tilecomp(ak0, ak1, av0, av1);
    ldt((kt + 3) & (NT - 1), dk0, dk1, dv0, dv1);
    tilecomp(bk0, bk1, bv0, bv1);
    ak0 = ck0; ak1 = ck1; av0 = cv0; av1 = cv1;
    bk0 = dk0; bk1 = dk1; bv0 = dv0; bv1 = dv1;
  }

  // epilogue: rescale to the true max (p_eff <= 1), publish split result to LDS
  float scale = __builtin_amdgcn_exp2f(m - mtrue);
  l *= scale;
  l = l + __shfl_xor(l, 32);

  // lane(n2,h) reg r -> qrow=n2, d=(r&3)+8*(r>>2)+4h; b128 stores into padded rows
#pragma unroll
  for (int bb = 0; bb < 4; ++bb) {
    floatx4 pv = {o[4 * bb + 0] * scale, o[4 * bb + 1] * scale,
                  o[4 * bb + 2] * scale, o[4 * bb + 3] * scale};
    *(floatx4*)&sO[w * 1152 + n2 * 36 + 8 * bb + 4 * h] = pv;
  }
  if (h == 0) {
    sM[w * 32 + n2] = mtrue;
    sL[w * 32 + n2] = l;
  }
  __syncthreads();

  // in-block merge of the 8 splits: 32 rows x 32 d = 1024 outputs, 512 threads x 2
#pragma unroll
  for (int it = 0; it < 2; ++it) {
    int idx = it * 512 + t;
    int qr = idx >> 5, d = idx & 31;
    float mv[NSPLIT];
    float ms = -__builtin_huge_valf();
#pragma unroll
    for (int w2 = 0; w2 < NSPLIT; ++w2) {
      mv[w2] = sM[w2 * 32 + qr];
      ms = fmaxf(ms, mv[w2]);
    }
    float L = 0.f, O = 0.f;
#pragma unroll
    for (int w2 = 0; w2 < NSPLIT; ++w2) {
      float ww = __builtin_amdgcn_exp2f(mv[w2] - ms);
      L += ww * sL[w2 * 32 + qr];
      O += ww * sO[w2 * 1152 + qr * 36 + d];
    }
    out[(size_t)(qrow0 + qr) * HD + d] = O * SCALING / L;
  }
}

extern "C" void kernel_launch(void* const* d_in, const int* in_sizes, int n_in,
                              void* d_out, int out_size, void* d_ws, size_t ws_size,
                              hipStream_t stream) {
  const float* x  = (const float*)d_in[0];
  const float* Wq = (const float*)d_in[1];
  const float* Wk = (const float*)d_in[2];
  const float* Wv = (const float*)d_in[3];
  float* out = (float*)d_out;

  _Float16* qw  = (_Float16*)d_ws;          // [16384][32]
  _Float16* kw  = qw + NQROW * HD;          // [16384][32]
  _Float16* vt2 = kw + NQROW * HD;          // [4][512][32][8] key-tiled V

  qkv_kernel<<<256, 256, 0, stream>>>(x, Wq, Wk, Wv, qw, kw, vt2);
  attn_kernel<<<512, 512, 0, stream>>>(qw, kw, vt2, out);
}